// Round 1
// baseline (680.699 us; speedup 1.0000x reference)
//
#include <hip/hip_runtime.h>
#include <math.h>

#define DHID 2048
#define TOK 256
#define NHEAD 16
#define HDIM 128
#define NEXP 64
#define KSEL 8
#define FFD 1024
#define RMSEPS 1e-5f
#define ATTNSCALE 0.08838834764831845f

typedef short bf16x8 __attribute__((ext_vector_type(8)));
typedef float f32x4 __attribute__((ext_vector_type(4)));

__device__ __forceinline__ float bf2f(unsigned short u){
  union { unsigned int u; float f; } c; c.u = ((unsigned int)u)<<16; return c.f;
}
__device__ __forceinline__ unsigned short f2bf(float f){
  union { float f; unsigned int u; } c; c.f = f;
  unsigned int u = c.u + 0x7fffu + ((c.u>>16)&1u);
  return (unsigned short)(u>>16);
}
__device__ __forceinline__ unsigned int pk2(float a, float b){
  return (unsigned int)f2bf(a) | ((unsigned int)f2bf(b)<<16);
}

// ---------------- RMSNorm (bf16 out + optional f32 out) ----------------
__global__ __launch_bounds__(256) void rms_kernel(const float* __restrict__ x,
    const float* __restrict__ w, unsigned short* __restrict__ obf,
    float* __restrict__ of32)
{
  int row = blockIdx.x, tid = threadIdx.x;
  const float* xr = x + (size_t)row*DHID;
  float4 a = *(const float4*)(xr + tid*8);
  float4 b = *(const float4*)(xr + tid*8 + 4);
  float ss = a.x*a.x+a.y*a.y+a.z*a.z+a.w*a.w + b.x*b.x+b.y*b.y+b.z*b.z+b.w*b.w;
  #pragma unroll
  for(int o=32;o>0;o>>=1) ss += __shfl_down(ss,o);
  __shared__ float red[4];
  if((tid&63)==0) red[tid>>6]=ss;
  __syncthreads();
  float r = rsqrtf((red[0]+red[1]+red[2]+red[3])*(1.0f/DHID) + RMSEPS);
  float v[8] = {a.x,a.y,a.z,a.w,b.x,b.y,b.z,b.w};
  unsigned short ob[8];
  #pragma unroll
  for(int j=0;j<8;j++){
    float val = v[j]*r*w[tid*8+j];
    ob[j]=f2bf(val);
    if(of32) of32[(size_t)row*DHID + tid*8 + j] = val;
  }
  uint4 o4;
  o4.x = (unsigned int)ob[0] | ((unsigned int)ob[1]<<16);
  o4.y = (unsigned int)ob[2] | ((unsigned int)ob[3]<<16);
  o4.z = (unsigned int)ob[4] | ((unsigned int)ob[5]<<16);
  o4.w = (unsigned int)ob[6] | ((unsigned int)ob[7]<<16);
  *(uint4*)(obf + (size_t)row*DHID + tid*8) = o4;
}

// ---------------- RoPE cos/sin table [256][64] ----------------
__global__ void rope_table_kernel(float* __restrict__ cs, float* __restrict__ sn){
  int i = blockIdx.x*256 + threadIdx.x;  // 16384
  int s = i>>6, j = i&63;
  float invf = powf(10000.0f, -(float)j*(1.0f/64.0f));
  float ang = (float)s * invf;
  cs[i] = cosf(ang); sn[i] = sinf(ang);
}

// ---------------- fused QKV GEMM: C[s,o] = sum_d xn[s,d]*W[o,d] ----------------
// BM=BN=BK=64, 4 waves (2x2), wave tile 32x32 via 16x16x32 bf16 MFMA.
__global__ __launch_bounds__(256) void gemm_qkv_kernel(
    const unsigned short* __restrict__ A,
    const float* __restrict__ qw, const float* __restrict__ kw, const float* __restrict__ vw,
    float* __restrict__ qo, float* __restrict__ ko, float* __restrict__ vo)
{
  int nt = blockIdx.x, mt = blockIdx.y;
  int which = nt>>5, nb = nt&31;
  const float* W = (which==0)? qw : (which==1)? kw : vw;
  float* OUT = (which==0)? qo : (which==1)? ko : vo;
  int n0 = nb*64, m0 = mt*64;
  __shared__ unsigned short As[64*64];
  __shared__ unsigned short Bs[64*64];
  int tid = threadIdx.x;
  int wid = tid>>6, lane = tid&63;
  int wm = wid>>1, wn = wid&1;
  int lr = lane&15, lg = lane>>4;
  int sr = tid>>2, sq = tid&3;
  f32x4 acc[2][2] = {};
  const unsigned short* Ap = A + (size_t)(m0+sr)*DHID + sq*16;
  const float* Bp = W + (size_t)(n0+sr)*DHID + sq*16;
  for(int k0=0;k0<DHID;k0+=64){
    uint4 a0 = *(const uint4*)(Ap + k0);
    uint4 a1 = *(const uint4*)(Ap + k0 + 8);
    float4 b0 = *(const float4*)(Bp + k0);
    float4 b1 = *(const float4*)(Bp + k0 + 4);
    float4 b2 = *(const float4*)(Bp + k0 + 8);
    float4 b3 = *(const float4*)(Bp + k0 + 12);
    int x7 = sr&7;
    *(uint4*)&As[sr*64 + (((sq*2)  ^ x7)*8)] = a0;
    *(uint4*)&As[sr*64 + (((sq*2+1)^ x7)*8)] = a1;
    uint4 p0 = make_uint4(pk2(b0.x,b0.y),pk2(b0.z,b0.w),pk2(b1.x,b1.y),pk2(b1.z,b1.w));
    uint4 p1 = make_uint4(pk2(b2.x,b2.y),pk2(b2.z,b2.w),pk2(b3.x,b3.y),pk2(b3.z,b3.w));
    *(uint4*)&Bs[sr*64 + (((sq*2)  ^ x7)*8)] = p0;
    *(uint4*)&Bs[sr*64 + (((sq*2+1)^ x7)*8)] = p1;
    __syncthreads();
    #pragma unroll
    for(int ki=0;ki<2;ki++){
      bf16x8 af[2], bfr[2];
      #pragma unroll
      for(int mi=0;mi<2;mi++){
        int r = wm*32 + mi*16 + lr;
        af[mi] = *(const bf16x8*)&As[r*64 + (((ki*4+lg)^(r&7))*8)];
      }
      #pragma unroll
      for(int ni=0;ni<2;ni++){
        int r = wn*32 + ni*16 + lr;
        bfr[ni] = *(const bf16x8*)&Bs[r*64 + (((ki*4+lg)^(r&7))*8)];
      }
      #pragma unroll
      for(int mi=0;mi<2;mi++)
        #pragma unroll
        for(int ni=0;ni<2;ni++)
          acc[mi][ni] = __builtin_amdgcn_mfma_f32_16x16x32_bf16(af[mi], bfr[ni], acc[mi][ni], 0,0,0);
    }
    __syncthreads();
  }
  #pragma unroll
  for(int mi=0;mi<2;mi++){
    #pragma unroll
    for(int ni=0;ni<2;ni++){
      int col = n0 + wn*32 + ni*16 + lr;
      int rowb = m0 + wm*32 + mi*16 + lg*4;
      #pragma unroll
      for(int rg=0;rg<4;rg++)
        OUT[(size_t)(rowb+rg)*DHID + col] = acc[mi][ni][rg];
    }
  }
}

// ---------------- O-proj GEMM (A f32->bf16 staged) + residual, dual store ----------------
__global__ __launch_bounds__(256) void gemm_o_kernel(const float* __restrict__ A,
  const float* __restrict__ W, const float* __restrict__ X,
  float* __restrict__ H, float* __restrict__ O)
{
  int nb = blockIdx.x, mt = blockIdx.y;
  int n0 = nb*64, m0 = mt*64;
  __shared__ unsigned short As[64*64];
  __shared__ unsigned short Bs[64*64];
  int tid = threadIdx.x;
  int wid = tid>>6, lane = tid&63;
  int wm = wid>>1, wn = wid&1;
  int lr = lane&15, lg = lane>>4;
  int sr = tid>>2, sq = tid&3;
  f32x4 acc[2][2] = {};
  const float* Ap = A + (size_t)(m0+sr)*DHID + sq*16;
  const float* Bp = W + (size_t)(n0+sr)*DHID + sq*16;
  for(int k0=0;k0<DHID;k0+=64){
    float4 a0=*(const float4*)(Ap+k0),   a1=*(const float4*)(Ap+k0+4);
    float4 a2=*(const float4*)(Ap+k0+8), a3=*(const float4*)(Ap+k0+12);
    float4 b0=*(const float4*)(Bp+k0),   b1=*(const float4*)(Bp+k0+4);
    float4 b2=*(const float4*)(Bp+k0+8), b3=*(const float4*)(Bp+k0+12);
    int x7 = sr&7;
    uint4 pa0 = make_uint4(pk2(a0.x,a0.y),pk2(a0.z,a0.w),pk2(a1.x,a1.y),pk2(a1.z,a1.w));
    uint4 pa1 = make_uint4(pk2(a2.x,a2.y),pk2(a2.z,a2.w),pk2(a3.x,a3.y),pk2(a3.z,a3.w));
    uint4 pb0 = make_uint4(pk2(b0.x,b0.y),pk2(b0.z,b0.w),pk2(b1.x,b1.y),pk2(b1.z,b1.w));
    uint4 pb1 = make_uint4(pk2(b2.x,b2.y),pk2(b2.z,b2.w),pk2(b3.x,b3.y),pk2(b3.z,b3.w));
    *(uint4*)&As[sr*64 + (((sq*2)  ^ x7)*8)] = pa0;
    *(uint4*)&As[sr*64 + (((sq*2+1)^ x7)*8)] = pa1;
    *(uint4*)&Bs[sr*64 + (((sq*2)  ^ x7)*8)] = pb0;
    *(uint4*)&Bs[sr*64 + (((sq*2+1)^ x7)*8)] = pb1;
    __syncthreads();
    #pragma unroll
    for(int ki=0;ki<2;ki++){
      bf16x8 af[2], bfr[2];
      #pragma unroll
      for(int mi=0;mi<2;mi++){
        int r = wm*32 + mi*16 + lr;
        af[mi] = *(const bf16x8*)&As[r*64 + (((ki*4+lg)^(r&7))*8)];
      }
      #pragma unroll
      for(int ni=0;ni<2;ni++){
        int r = wn*32 + ni*16 + lr;
        bfr[ni] = *(const bf16x8*)&Bs[r*64 + (((ki*4+lg)^(r&7))*8)];
      }
      #pragma unroll
      for(int mi=0;mi<2;mi++)
        #pragma unroll
        for(int ni=0;ni<2;ni++)
          acc[mi][ni] = __builtin_amdgcn_mfma_f32_16x16x32_bf16(af[mi], bfr[ni], acc[mi][ni], 0,0,0);
    }
    __syncthreads();
  }
  #pragma unroll
  for(int mi=0;mi<2;mi++){
    #pragma unroll
    for(int ni=0;ni<2;ni++){
      int col = n0 + wn*32 + ni*16 + lr;
      int rowb = m0 + wm*32 + mi*16 + lg*4;
      #pragma unroll
      for(int rg=0;rg<4;rg++){
        size_t idx = (size_t)(rowb+rg)*DHID + col;
        float v = acc[mi][ni][rg] + X[idx];
        H[idx] = v; O[idx] = v;
      }
    }
  }
}

// ---------------- QK RMSNorm (full 2048) + RoPE, f32 out [head][tok][128] ----------------
__global__ __launch_bounds__(256) void qknorm_rope_kernel(const float* __restrict__ in,
   const float* __restrict__ w, const float* __restrict__ cs, const float* __restrict__ sn,
   float* __restrict__ out)
{
  int t = blockIdx.x, tid = threadIdx.x;
  __shared__ float xs[DHID];
  const float* xr = in + (size_t)t*DHID;
  float4 a = *(const float4*)(xr + tid*8);
  float4 b = *(const float4*)(xr + tid*8 + 4);
  *(float4*)&xs[tid*8] = a; *(float4*)&xs[tid*8+4] = b;
  float ss = a.x*a.x+a.y*a.y+a.z*a.z+a.w*a.w + b.x*b.x+b.y*b.y+b.z*b.z+b.w*b.w;
  #pragma unroll
  for(int o=32;o>0;o>>=1) ss += __shfl_down(ss,o);
  __shared__ float red[4];
  if((tid&63)==0) red[tid>>6]=ss;
  __syncthreads();
  float r = rsqrtf((red[0]+red[1]+red[2]+red[3])*(1.0f/DHID) + RMSEPS);
  int hh = tid>>4, jb = (tid&15)*4;
  #pragma unroll
  for(int p=0;p<4;p++){
    int j = jb+p;
    int i0 = hh*HDIM + j, i1 = i0+64;
    float va = xs[i0]*r*w[i0];
    float vb = xs[i1]*r*w[i1];
    float c = cs[t*64+j], s = sn[t*64+j];
    out[((size_t)(hh*TOK + t))*HDIM + j]    = va*c - vb*s;
    out[((size_t)(hh*TOK + t))*HDIM + j+64] = vb*c + va*s;
  }
}

// ---------------- V reshape to [head][tok][128] f32 ----------------
__global__ __launch_bounds__(256) void vreshape_kernel(const float* __restrict__ v,
    float* __restrict__ vh)
{
  int t = blockIdx.x, tid = threadIdx.x;
  int i = tid*8;
  int hh = i>>7, d0 = i&127;
  float4 a = *(const float4*)(v + (size_t)t*DHID + i);
  float4 b = *(const float4*)(v + (size_t)t*DHID + i + 4);
  *(float4*)(vh + ((size_t)(hh*TOK+t))*HDIM + d0)     = a;
  *(float4*)(vh + ((size_t)(hh*TOK+t))*HDIM + d0 + 4) = b;
}

// ---------------- causal attention, f32, 16 q-rows per block ----------------
__global__ __launch_bounds__(256) void attn_kernel(const float* __restrict__ qh,
  const float* __restrict__ kh, const float* __restrict__ vh, float* __restrict__ ctx)
{
  int head = blockIdx.x>>4, qt = blockIdx.x&15;
  __shared__ float qs[16][132];
  __shared__ float sc[16][260];
  __shared__ float red[16][16];
  __shared__ float rmx[16], rsm[16];
  int tid = threadIdx.x;
  {
    int r = tid>>4, c = (tid&15)*8;
    const float* src = qh + ((size_t)(head*TOK + qt*16 + r))*HDIM + c;
    *(float4*)&qs[r][c]   = *(const float4*)(src);
    *(float4*)&qs[r][c+4] = *(const float4*)(src+4);
  }
  __syncthreads();
  int qi = tid&15, kk = tid>>4;
  int qg = qt*16 + qi;
  for(int k=kk; k<=qg; k+=16){
    const float* kp = kh + ((size_t)(head*TOK + k))*HDIM;
    float d = 0.f;
    #pragma unroll 8
    for(int c=0;c<128;c+=4){
      float4 kv = *(const float4*)(kp + c);
      float4 qv = *(const float4*)&qs[qi][c];
      d += qv.x*kv.x + qv.y*kv.y + qv.z*kv.z + qv.w*kv.w;
    }
    sc[qi][k] = d*ATTNSCALE;
  }
  float m = -1e30f;
  for(int k=kk;k<=qg;k+=16) m = fmaxf(m, sc[qi][k]);
  red[qi][kk] = m;
  __syncthreads();
  if(kk==0){
    float mm=-1e30f;
    #pragma unroll
    for(int j=0;j<16;j++) mm = fmaxf(mm, red[qi][j]);
    rmx[qi]=mm;
  }
  __syncthreads();
  float mm = rmx[qi];
  float s = 0.f;
  for(int k=kk;k<=qg;k+=16){ float pp = expf(sc[qi][k]-mm); sc[qi][k]=pp; s+=pp; }
  red[qi][kk]=s;
  __syncthreads();
  if(kk==0){
    float t_=0.f;
    #pragma unroll
    for(int j=0;j<16;j++) t_ += red[qi][j];
    rsm[qi]=t_;
  }
  __syncthreads();
  int dg = kk;
  float acc[8]={0,0,0,0,0,0,0,0};
  const float* vp = vh + (size_t)head*TOK*HDIM + dg*8;
  for(int k=0;k<=qg;k++){
    float p = sc[qi][k];
    float4 v0 = *(const float4*)(vp + (size_t)k*HDIM);
    float4 v1 = *(const float4*)(vp + (size_t)k*HDIM + 4);
    acc[0]+=p*v0.x; acc[1]+=p*v0.y; acc[2]+=p*v0.z; acc[3]+=p*v0.w;
    acc[4]+=p*v1.x; acc[5]+=p*v1.y; acc[6]+=p*v1.z; acc[7]+=p*v1.w;
  }
  float inv = 1.0f/rsm[qi];
  float* op = ctx + ((size_t)(qt*16+qi))*DHID + head*HDIM + dg*8;
  *(float4*)(op)   = make_float4(acc[0]*inv, acc[1]*inv, acc[2]*inv, acc[3]*inv);
  *(float4*)(op+4) = make_float4(acc[4]*inv, acc[5]*inv, acc[6]*inv, acc[7]*inv);
}

// ---------------- router: logits, softmax f32, exact top-8, expert lists ----------------
__global__ __launch_bounds__(256) void router_kernel(const float* __restrict__ hn,
    const float* __restrict__ rw, int* __restrict__ counts, int* __restrict__ toklist,
    float* __restrict__ wlist)
{
  int t = blockIdx.x, tid = threadIdx.x;
  __shared__ float xs[DHID];
  __shared__ float part[NEXP*4];
  __shared__ float probs[NEXP];
  *(float4*)&xs[tid*8]   = *(const float4*)(hn + (size_t)t*DHID + tid*8);
  *(float4*)&xs[tid*8+4] = *(const float4*)(hn + (size_t)t*DHID + tid*8+4);
  __syncthreads();
  int e = tid&63, c = tid>>6;
  const float* w = rw + (size_t)e*DHID + c*512;
  const float* xc = xs + c*512;
  float d = 0.f;
  for(int i=0;i<512;i+=4){
    float4 wv = *(const float4*)(w+i);
    d += xc[i]*wv.x + xc[i+1]*wv.y + xc[i+2]*wv.z + xc[i+3]*wv.w;
  }
  part[c*64 + e] = d;
  __syncthreads();
  if(tid<64){
    float logit = part[tid] + part[64+tid] + part[128+tid] + part[192+tid];
    float m = logit;
    #pragma unroll
    for(int o=32;o>0;o>>=1) m = fmaxf(m, __shfl_xor(m,o));
    float p = expf(logit - m);
    float s = p;
    #pragma unroll
    for(int o=32;o>0;o>>=1) s += __shfl_xor(s,o);
    probs[tid] = p/s;
  }
  __syncthreads();
  if(tid==0){
    unsigned long long used = 0ull;
    for(int r=0;r<KSEL;r++){
      float best = -1.f; int bi = 0;
      for(int j=0;j<NEXP;j++){
        if(!((used>>j)&1ull) && probs[j]>best){ best=probs[j]; bi=j; }
      }
      used |= (1ull<<bi);
      int slot = atomicAdd(&counts[bi],1);
      toklist[bi*TOK+slot] = t;
      wlist[bi*TOK+slot] = best;
    }
  }
}

// ---------------- exclusive prefix scan of counts (64) ----------------
__global__ void scan_kernel(const int* __restrict__ counts, int* __restrict__ offs){
  int e = threadIdx.x;
  int c = counts[e];
  int v = c;
  #pragma unroll
  for(int o=1;o<64;o<<=1){
    int n = __shfl_up(v,o);
    if(e>=o) v += n;
  }
  offs[e] = v - c;
}

// ---------------- MoE gate+up: mid = silu(g)*u*combine, bf16 compact ----------------
__global__ __launch_bounds__(256) void moe_gateup_kernel(const unsigned short* __restrict__ hnb,
  const float* __restrict__ gw, const float* __restrict__ uw,
  const int* __restrict__ counts, const int* __restrict__ offs,
  const int* __restrict__ toklist, const float* __restrict__ wlist,
  unsigned short* __restrict__ mid)
{
  int fb = blockIdx.x, e = blockIdx.y, mc = blockIdx.z;
  int cnt = counts[e];
  if(mc*32 >= cnt) return;
  int base = offs[e];
  __shared__ unsigned short As[32*64];
  __shared__ unsigned short Bg[64*64];
  __shared__ unsigned short Bu[64*64];
  __shared__ int toks[32];
  __shared__ float cw[32];
  int tid = threadIdx.x;
  if(tid<32){
    int sl = mc*32 + tid;
    int cl = (sl<cnt)? sl : (cnt-1);
    toks[tid] = toklist[e*TOK + cl];
    cw[tid]   = (sl<cnt)? wlist[e*TOK+sl] : 0.0f;
  }
  __syncthreads();
  int wid=tid>>6, lane=tid&63, wm=wid>>1, wn=wid&1, lr=lane&15, lg=lane>>4;
  int arow=tid>>3, ac=tid&7;
  int sr=tid>>2, sq=tid&3;
  const unsigned short* Ap = hnb + (size_t)toks[arow]*DHID + ac*8;
  const float* Gp = gw + ((size_t)e*FFD + fb*64 + sr)*DHID + sq*16;
  const float* Up = uw + ((size_t)e*FFD + fb*64 + sr)*DHID + sq*16;
  f32x4 ag[2]={}, au[2]={};
  for(int k0=0;k0<DHID;k0+=64){
    uint4 av = *(const uint4*)(Ap + k0);
    float4 g0=*(const float4*)(Gp+k0),   g1=*(const float4*)(Gp+k0+4);
    float4 g2=*(const float4*)(Gp+k0+8), g3=*(const float4*)(Gp+k0+12);
    float4 u0=*(const float4*)(Up+k0),   u1=*(const float4*)(Up+k0+4);
    float4 u2=*(const float4*)(Up+k0+8), u3=*(const float4*)(Up+k0+12);
    int xa = arow&7, xb = sr&7;
    *(uint4*)&As[arow*64 + ((ac^xa)*8)] = av;
    uint4 pg0 = make_uint4(pk2(g0.x,g0.y),pk2(g0.z,g0.w),pk2(g1.x,g1.y),pk2(g1.z,g1.w));
    uint4 pg1 = make_uint4(pk2(g2.x,g2.y),pk2(g2.z,g2.w),pk2(g3.x,g3.y),pk2(g3.z,g3.w));
    uint4 pu0 = make_uint4(pk2(u0.x,u0.y),pk2(u0.z,u0.w),pk2(u1.x,u1.y),pk2(u1.z,u1.w));
    uint4 pu1 = make_uint4(pk2(u2.x,u2.y),pk2(u2.z,u2.w),pk2(u3.x,u3.y),pk2(u3.z,u3.w));
    *(uint4*)&Bg[sr*64 + (((sq*2)  ^ xb)*8)] = pg0;
    *(uint4*)&Bg[sr*64 + (((sq*2+1)^ xb)*8)] = pg1;
    *(uint4*)&Bu[sr*64 + (((sq*2)  ^ xb)*8)] = pu0;
    *(uint4*)&Bu[sr*64 + (((sq*2+1)^ xb)*8)] = pu1;
    __syncthreads();
    #pragma unroll
    for(int ki=0;ki<2;ki++){
      int ar = wm*16 + lr;
      bf16x8 af = *(const bf16x8*)&As[ar*64 + (((ki*4+lg)^(ar&7))*8)];
      #pragma unroll
      for(int ni=0;ni<2;ni++){
        int br = wn*32 + ni*16 + lr;
        int bo = br*64 + (((ki*4+lg)^(br&7))*8);
        bf16x8 bg = *(const bf16x8*)&Bg[bo];
        bf16x8 bu = *(const bf16x8*)&Bu[bo];
        ag[ni] = __builtin_amdgcn_mfma_f32_16x16x32_bf16(af,bg,ag[ni],0,0,0);
        au[ni] = __builtin_amdgcn_mfma_f32_16x16x32_bf16(af,bu,au[ni],0,0,0);
      }
    }
    __syncthreads();
  }
  #pragma unroll
  for(int ni=0;ni<2;ni++){
    int f = fb*64 + wn*32 + ni*16 + lr;
    #pragma unroll
    for(int rg=0;rg<4;rg++){
      int sl = wm*16 + lg*4 + rg;
      int slot = mc*32 + sl;
      if(slot < cnt){
        float g = ag[ni][rg], u = au[ni][rg];
        float mval = g/(1.0f+expf(-g))*u*cw[sl];
        mid[((size_t)(base+slot))*FFD + f] = f2bf(mval);
      }
    }
  }
}

// ---------------- MoE down: atomicAdd into out (pre-initialized to h) ----------------
__global__ __launch_bounds__(256) void moe_down_kernel(const unsigned short* __restrict__ mid,
  const float* __restrict__ dwn, const int* __restrict__ counts, const int* __restrict__ offs,
  const int* __restrict__ toklist, float* __restrict__ out)
{
  int nb=blockIdx.x, e=blockIdx.y, mc=blockIdx.z;
  int cnt=counts[e];
  if(mc*32>=cnt) return;
  int base=offs[e];
  __shared__ unsigned short As[32*64];
  __shared__ unsigned short Bs[64*64];
  __shared__ int toks[32];
  int tid=threadIdx.x;
  if(tid<32){ int sl=mc*32+tid; toks[tid]=toklist[e*TOK + ((sl<cnt)?sl:(cnt-1))]; }
  __syncthreads();
  int wid=tid>>6, lane=tid&63, wm=wid>>1, wn=wid&1, lr=lane&15, lg=lane>>4;
  int arow=tid>>3, ac=tid&7;
  int sr=tid>>2, sq=tid&3;
  int sla = mc*32+arow; if(sla>=cnt) sla=cnt-1;
  const unsigned short* Ap = mid + ((size_t)(base+sla))*FFD + ac*8;
  const float* Bp = dwn + ((size_t)e*DHID + nb*64 + sr)*FFD + sq*16;
  f32x4 acc[2]={};
  for(int k0=0;k0<FFD;k0+=64){
    uint4 av = *(const uint4*)(Ap+k0);
    float4 b0=*(const float4*)(Bp+k0),   b1=*(const float4*)(Bp+k0+4);
    float4 b2=*(const float4*)(Bp+k0+8), b3=*(const float4*)(Bp+k0+12);
    int xa=arow&7, xb=sr&7;
    *(uint4*)&As[arow*64+((ac^xa)*8)] = av;
    uint4 p0=make_uint4(pk2(b0.x,b0.y),pk2(b0.z,b0.w),pk2(b1.x,b1.y),pk2(b1.z,b1.w));
    uint4 p1=make_uint4(pk2(b2.x,b2.y),pk2(b2.z,b2.w),pk2(b3.x,b3.y),pk2(b3.z,b3.w));
    *(uint4*)&Bs[sr*64+(((sq*2)^xb)*8)] = p0;
    *(uint4*)&Bs[sr*64+(((sq*2+1)^xb)*8)] = p1;
    __syncthreads();
    #pragma unroll
    for(int ki=0;ki<2;ki++){
      int ar=wm*16+lr;
      bf16x8 af=*(const bf16x8*)&As[ar*64+(((ki*4+lg)^(ar&7))*8)];
      #pragma unroll
      for(int ni=0;ni<2;ni++){
        int br=wn*32+ni*16+lr;
        bf16x8 bb=*(const bf16x8*)&Bs[br*64+(((ki*4+lg)^(br&7))*8)];
        acc[ni]=__builtin_amdgcn_mfma_f32_16x16x32_bf16(af,bb,acc[ni],0,0,0);
      }
    }
    __syncthreads();
  }
  #pragma unroll
  for(int ni=0;ni<2;ni++){
    int d = nb*64 + wn*32 + ni*16 + lr;
    #pragma unroll
    for(int rg=0;rg<4;rg++){
      int sl=wm*16+lg*4+rg, slot=mc*32+sl;
      if(slot<cnt) atomicAdd(out + (size_t)toks[sl]*DHID + d, acc[ni][rg]);
    }
  }
}

extern "C" void kernel_launch(void* const* d_in, const int* in_sizes, int n_in,
                              void* d_out, int out_size, void* d_ws, size_t ws_size,
                              hipStream_t stream)
{
  (void)in_sizes; (void)n_in; (void)out_size; (void)ws_size;
  const float* x    = (const float*)d_in[0];
  const float* ln1w = (const float*)d_in[1];
  const float* qw   = (const float*)d_in[2];
  const float* kw   = (const float*)d_in[3];
  const float* vw   = (const float*)d_in[4];
  const float* ow   = (const float*)d_in[5];
  const float* qnw  = (const float*)d_in[6];
  const float* knw  = (const float*)d_in[7];
  const float* ln2w = (const float*)d_in[8];
  const float* rw   = (const float*)d_in[9];
  const float* gw   = (const float*)d_in[10];
  const float* uw   = (const float*)d_in[11];
  const float* dwn  = (const float*)d_in[12];
  float* out = (float*)d_out;

  char* p = (char*)d_ws;
  auto alloc = [&](size_t bytes)->void*{ void* r = (void*)p; p += (bytes + 255) & ~(size_t)255; return r; };
  unsigned short* xnb = (unsigned short*)alloc((size_t)TOK*DHID*2);
  float* qf   = (float*)alloc((size_t)TOK*DHID*4);
  float* kf   = (float*)alloc((size_t)TOK*DHID*4);
  float* vf   = (float*)alloc((size_t)TOK*DHID*4);
  float* qh   = (float*)alloc((size_t)TOK*DHID*4);
  float* kh   = (float*)alloc((size_t)TOK*DHID*4);
  float* vh   = (float*)alloc((size_t)TOK*DHID*4);
  float* ctx  = (float*)alloc((size_t)TOK*DHID*4);
  float* hbuf = (float*)alloc((size_t)TOK*DHID*4);
  float* hnf  = (float*)alloc((size_t)TOK*DHID*4);
  unsigned short* hnb = (unsigned short*)alloc((size_t)TOK*DHID*2);
  float* csb  = (float*)alloc((size_t)TOK*64*4);
  float* snb  = (float*)alloc((size_t)TOK*64*4);
  int* counts = (int*)alloc(NEXP*4);
  int* offs   = (int*)alloc(NEXP*4);
  int* toklist= (int*)alloc((size_t)NEXP*TOK*4);
  float* wlist= (float*)alloc((size_t)NEXP*TOK*4);
  unsigned short* mid = (unsigned short*)alloc((size_t)TOK*KSEL*FFD*2);

  rope_table_kernel<<<64,256,0,stream>>>(csb,snb);
  rms_kernel<<<TOK,256,0,stream>>>(x, ln1w, xnb, nullptr);
  gemm_qkv_kernel<<<dim3(96,4),256,0,stream>>>(xnb,qw,kw,vw,qf,kf,vf);
  qknorm_rope_kernel<<<TOK,256,0,stream>>>(qf,qnw,csb,snb,qh);
  qknorm_rope_kernel<<<TOK,256,0,stream>>>(kf,knw,csb,snb,kh);
  vreshape_kernel<<<TOK,256,0,stream>>>(vf,vh);
  attn_kernel<<<256,256,0,stream>>>(qh,kh,vh,ctx);
  gemm_o_kernel<<<dim3(32,4),256,0,stream>>>(ctx,ow,x,hbuf,out);
  rms_kernel<<<TOK,256,0,stream>>>(hbuf, ln2w, hnb, hnf);
  hipMemsetAsync(counts,0,NEXP*4,stream);
  router_kernel<<<TOK,256,0,stream>>>(hnf,rw,counts,toklist,wlist);
  scan_kernel<<<1,64,0,stream>>>(counts,offs);
  moe_gateup_kernel<<<dim3(16,NEXP,8),256,0,stream>>>(hnb,gw,uw,counts,offs,toklist,wlist,mid);
  moe_down_kernel<<<dim3(32,NEXP,8),256,0,stream>>>(mid,dwn,counts,offs,toklist,out);
}